// Round 12
// baseline (316.749 us; speedup 1.0000x reference)
//
#include <hip/hip_runtime.h>

typedef _Float16 f16x8 __attribute__((ext_vector_type(8)));
typedef float f32x4 __attribute__((ext_vector_type(4)));

__device__ __forceinline__ float h2f(unsigned short h) {
  return (float)__builtin_bit_cast(_Float16, h);
}
__device__ __forceinline__ unsigned short f2h(float f) {
  return __builtin_bit_cast(unsigned short, (_Float16)f);
}

__device__ __forceinline__ void gload_lds16(const void* g, void* l) {
  __builtin_amdgcn_global_load_lds(
      (const __attribute__((address_space(1))) void*)g,
      (__attribute__((address_space(3))) void*)l, 16, 0, 0);
}

// ---------------------------------------------------------------------------
// 128x256 tile GEMM, C = A @ Bt^T (fp16 MFMA, fp32 acc).
// r7/r9 core + B-DOUBLE-BUFFER with counted vmcnt: LDS = A 16K | B0 32K |
// B1 32K = 80KB -> still 2 blocks/CU (160KB exact). Per iter:
//   s_barrier(top) -> stage A[t] -> issue B[t+1] into buf^1 ->
//   counted vmcnt (certifies B[t] landed; t+1 prefetches stay in flight) ->
//   s_barrier -> compute from Bbuf[t&1].
// Ledger (in-order retirement): outstanding after issues = exactly the t+1
// prefetches (ASRC0: A[t]2+B[t+1]4 -> vmcnt(4) also lands A[t]; ASRC1:
// Aregs[t+1]4+B[t+1]4 -> vmcnt(8)). Last iter peels to vmcnt(0).
// WAR: B[t+1] writes buf whose readers finished before top barrier; A-writes
// separated from A-reads by the two barriers. lgkmcnt(0) before the compute
// barrier makes ds_writes visible (ASRC1).
// ASRC 0: A fp16 via global_load_lds.  ASRC 1: A fp32, T14 reg-prefetch+cvt.
// OUTMODE 0: fp32 + bias[col]
//         2: fp16 split-K partial (slice zt), no bias
//         3: fp16 exp(acc + bias[col]), normal [row][col] layout (Q path)
//         4: fp16 exp(acc + bias[col]), TRANSPOSED: ET[col][row], packed 8B
//         5: fp32 acc*sinv[row] + bias[col]  (fused row-softmax + out)
// ---------------------------------------------------------------------------
template <int ASRC, int OUTMODE>
__global__ __launch_bounds__(512, 4) void gemmt(
    const void* __restrict__ Av, const unsigned short* __restrict__ Bt,
    void* __restrict__ Cv, const float* __restrict__ bias,
    const float* __restrict__ sinv,
    int N, int K, int ldk, int gx, int gy, int nsplit,
    long sA, long sB, long sC)
{
  __shared__ alignas(16) unsigned char smem[81920];  // A 16K | B0 32K | B1 32K
  const int tid  = threadIdx.x;
  const int lane = tid & 63;
  const int wave = tid >> 6;
  const int waveM = wave >> 2;      // 0..1 (64 rows each)
  const int waveN = wave & 3;       // 0..3 (64 cols each)

  // bijective XCD swizzle (nwg % 8 == 0 for all launches here)
  const int nwg = (int)gridDim.x;
  const int cpx = nwg >> 3;
  const int wg  = (int)blockIdx.x;
  const int w   = (wg & 7) * cpx + (wg >> 3);
  const int x   = w % gx;
  const int rem = w / gx;
  const int y   = rem % gy;
  const int zt  = rem / gy;
  const int bz  = zt / nsplit;
  const int sp  = zt % nsplit;

  const int m0 = y * 128, n0 = x * 256;
  const size_t ldkB = (size_t)ldk * 2;
  const size_t ldkB64 = ldkB * 64, ldkB128 = ldkB * 128;

  // staging addresses (dst linear tid*16 (+8192); src inverse-swizzled)
  const int srow = tid >> 3;                         // 0..63
  const int scol = ((tid * 16) & 127) ^ ((srow & 7) << 4);   // fp16-bytes
  const char* ApR16 = nullptr;   // ASRC==0
  const char* ApR32 = nullptr;   // ASRC==1
  const char* BpR;
  {
    const char* Bb = (const char*)(Bt + (long)bz * sB + (long)sp * K) + (size_t)n0 * ldkB;
    BpR = Bb + (size_t)srow * ldkB + scol;
    if (ASRC == 0) {
      const char* Ab = (const char*)Av + ((long)bz * sA + (long)sp * K) * 2
                       + (size_t)m0 * ldkB;
      ApR16 = Ab + (size_t)srow * ldkB + scol;
    } else {
      const char* Ab = (const char*)Av + ((long)bz * sA + (long)sp * K) * 4
                       + (size_t)m0 * (size_t)ldk * 4;
      ApR32 = Ab + (size_t)srow * (size_t)ldk * 4 + (size_t)scol * 2;
    }
  }
  const unsigned oA0 = (unsigned)tid * 16;
  const size_t ldk32_64 = (size_t)ldk * 4 * 64;      // 64 rows of fp32

  // ds_read byte offsets (kk=0); kk=1 offset = kk0 ^ 64 (bits 4-6 swizzle field)
  int offA[4], offB[4];
  {
    const int q16 = (lane >> 4) << 4;
#pragma unroll
    for (int mi = 0; mi < 4; ++mi) {
      const int r = waveM * 64 + mi * 16 + (lane & 15);
      offA[mi] = r * 128 + (q16 ^ ((r & 7) << 4));
    }
#pragma unroll
    for (int ni = 0; ni < 4; ++ni) {
      const int r = waveN * 64 + ni * 16 + (lane & 15);
      offB[ni] = 16384 + r * 128 + (q16 ^ ((r & 7) << 4));
    }
  }

  f32x4 acc[4][4] = {};

  // T14 prefetch registers (ASRC==1): tile-kt fp32 A values live here at the
  // top of iteration kt.
  float4 pf0, pf1, pf2, pf3;
  if (ASRC == 1) {
    const char* s0 = ApR32;
    const char* s1 = s0 + ldk32_64;
    pf0 = *(const float4*)s0;  pf1 = *(const float4*)(s0 + 16);
    pf2 = *(const float4*)s1;  pf3 = *(const float4*)(s1 + 16);
  }

  const int nk = K >> 6;
  // prologue: B[0] -> Bbuf0
  gload_lds16(BpR,                     smem + 16384 + oA0);
  gload_lds16(BpR + ldkB64,            smem + 16384 + oA0 + 8192);
  gload_lds16(BpR + ldkB128,           smem + 16384 + oA0 + 16384);
  gload_lds16(BpR + ldkB128 + ldkB64,  smem + 16384 + oA0 + 24576);

  for (int kt = 0; kt < nk; ++kt) {
    const size_t kb = (size_t)kt * 128;              // fp16 bytes per K-tile
    // top barrier: separates prev compute's LDS reads from this iter's writes
    __builtin_amdgcn_sched_barrier(0);
    __builtin_amdgcn_s_barrier();
    __builtin_amdgcn_sched_barrier(0);
    if (ASRC == 0) {
      gload_lds16(ApR16 + kb,           smem + oA0);
      gload_lds16(ApR16 + ldkB64 + kb,  smem + oA0 + 8192);
    } else {
      // cvt tile-kt regs -> LDS (compiler auto-waits the reg deps only)
      unsigned short h0[8], h1[8];
      const float* fa0 = (const float*)&pf0; const float* fa1 = (const float*)&pf1;
      const float* fb0 = (const float*)&pf2; const float* fb1 = (const float*)&pf3;
#pragma unroll
      for (int e = 0; e < 4; ++e) {
        h0[e] = f2h(fa0[e]); h0[4 + e] = f2h(fa1[e]);
        h1[e] = f2h(fb0[e]); h1[4 + e] = f2h(fb1[e]);
      }
      *(uint4*)&smem[oA0]        = *(const uint4*)h0;
      *(uint4*)&smem[oA0 + 8192] = *(const uint4*)h1;
      // issue A-reg loads for kt+1 (before B so the next ds_write's auto-wait
      // leaves B[t+1] in flight)
      if (kt + 1 < nk) {
        const char* s0 = ApR32 + (size_t)(kt + 1) * 256;
        const char* s1 = s0 + ldk32_64;
        pf0 = *(const float4*)s0;  pf1 = *(const float4*)(s0 + 16);
        pf2 = *(const float4*)s1;  pf3 = *(const float4*)(s1 + 16);
      }
    }
    if (kt + 1 < nk) {
      const size_t kb1 = kb + 128;
      unsigned char* bd = smem + 16384 + (unsigned)((kt + 1) & 1) * 32768 + oA0;
      gload_lds16(BpR + kb1,                     bd);
      gload_lds16(BpR + ldkB64 + kb1,            bd + 8192);
      gload_lds16(BpR + ldkB128 + kb1,           bd + 16384);
      gload_lds16(BpR + ldkB128 + ldkB64 + kb1,  bd + 24576);
    }
    // counted wait: certify A[t] (ASRC0) / B[t] landed; t+1 prefetches remain
    if (ASRC == 0) {
      if (kt + 1 < nk) { asm volatile("s_waitcnt vmcnt(4)" ::: "memory"); }
      else             { asm volatile("s_waitcnt vmcnt(0)" ::: "memory"); }
    } else {
      if (kt + 1 < nk) { asm volatile("s_waitcnt vmcnt(8) lgkmcnt(0)" ::: "memory"); }
      else             { asm volatile("s_waitcnt vmcnt(0) lgkmcnt(0)" ::: "memory"); }
    }
    __builtin_amdgcn_sched_barrier(0);
    __builtin_amdgcn_s_barrier();
    __builtin_amdgcn_sched_barrier(0);

    const int bsel = (kt & 1) * 32768;
#pragma unroll
    for (int kk = 0; kk < 2; ++kk) {
      const int kx = kk << 6;
      f16x8 aF[4], bF[4];
#pragma unroll
      for (int mi = 0; mi < 4; ++mi) aF[mi] = *(const f16x8*)&smem[offA[mi] ^ kx];
#pragma unroll
      for (int ni = 0; ni < 4; ++ni) bF[ni] = *(const f16x8*)&smem[(offB[ni] ^ kx) + bsel];
#pragma unroll
      for (int mi = 0; mi < 4; ++mi)
#pragma unroll
        for (int ni = 0; ni < 4; ++ni)
          acc[mi][ni] = __builtin_amdgcn_mfma_f32_16x16x32_f16(aF[mi], bF[ni], acc[mi][ni], 0, 0, 0);
    }
  }

  // epilogue
  const int rb = (lane >> 4) * 4;
  const int cb_ = lane & 15;
  const long zout = (OUTMODE == 2) ? (long)zt : (long)bz;
#pragma unroll
  for (int m = 0; m < 4; ++m) {
#pragma unroll
    for (int n = 0; n < 4; ++n) {
      const int col = n0 + waveN * 64 + n * 16 + cb_;
      const int row0 = m0 + waveM * 64 + m * 16 + rb;
      if (OUTMODE == 4) {
        const float badd = bias[col];
        unsigned short o4[4];
#pragma unroll
        for (int r = 0; r < 4; ++r) o4[r] = f2h(__expf(acc[m][n][r] + badd));
        *(uint2*)((unsigned short*)Cv + zout * sC + ((size_t)col << 12) + row0) =
            *(const uint2*)o4;
      } else if (OUTMODE == 3) {
        const float badd = bias[col];
#pragma unroll
        for (int r = 0; r < 4; ++r)
          ((unsigned short*)Cv)[zout * sC + (size_t)(row0 + r) * N + col] =
              f2h(__expf(acc[m][n][r] + badd));
      } else if (OUTMODE == 2) {
#pragma unroll
        for (int r = 0; r < 4; ++r)
          ((unsigned short*)Cv)[zout * sC + (size_t)(row0 + r) * N + col] = f2h(acc[m][n][r]);
      } else if (OUTMODE == 5) {
        const float badd = bias[col];
        const float4 sv4 = *(const float4*)&sinv[zout * 4096 + row0];
        const float* svp = (const float*)&sv4;
#pragma unroll
        for (int r = 0; r < 4; ++r)
          ((float*)Cv)[zout * sC + (size_t)(row0 + r) * N + col] = acc[m][n][r] * svp[r] + badd;
      } else {
        const float badd = bias[col];
#pragma unroll
        for (int r = 0; r < 4; ++r)
          ((float*)Cv)[zout * sC + (size_t)(row0 + r) * N + col] = acc[m][n][r] + badd;
      }
    }
  }
}

// ---------------------------------------------------------------------------
// Weight transpose + fp16: WT[c][r] = f16(W[r][c]), 1024x1024
// ---------------------------------------------------------------------------
__global__ __launch_bounds__(256) void w_trh(
    const float* __restrict__ W, unsigned short* __restrict__ WT)
{
  __shared__ unsigned short tile[64][73];
  const int c0 = blockIdx.x * 64;
  const int r0 = blockIdx.y * 64;
  const int tid = threadIdx.x;
  const int r = tid >> 2;
  const int cq = (tid & 3) * 16;
#pragma unroll
  for (int i = 0; i < 4; ++i) {
    const int c = cq + i * 4;
    const float4 v = *(const float4*)&W[(size_t)(r0 + r) * 1024 + c0 + c];
    tile[r][c + 0] = f2h(v.x);
    tile[r][c + 1] = f2h(v.y);
    tile[r][c + 2] = f2h(v.z);
    tile[r][c + 3] = f2h(v.w);
  }
  __syncthreads();
  const int c = tid >> 2;
  const int rq = (tid & 3) * 16;
  unsigned short outv[16];
#pragma unroll
  for (int j = 0; j < 16; ++j) outv[j] = tile[rq + j][c];
  unsigned short* Tb = WT + (size_t)(c0 + c) * 1024 + r0 + rq;
  ((uint4*)Tb)[0] = ((const uint4*)outv)[0];
  ((uint4*)Tb)[1] = ((const uint4*)outv)[1];
}

// ---------------------------------------------------------------------------
// Row-sum reciprocal, rows of 1024 fp16 (Eq): si[row] = 1/sum(E[row][:])
// ---------------------------------------------------------------------------
__global__ __launch_bounds__(256) void rsum_inv_1k(
    const unsigned short* __restrict__ E, float* __restrict__ si)
{
  const int row = blockIdx.x;
  const int tid = threadIdx.x;
  const uint2 u = ((const uint2*)(E + (size_t)row * 1024))[tid];
  float s = (h2f(u.x & 0xffff) + h2f(u.x >> 16)) +
            (h2f(u.y & 0xffff) + h2f(u.y >> 16));
#pragma unroll
  for (int o = 32; o >= 1; o >>= 1) s += __shfl_xor(s, o);
  __shared__ float rs[4];
  if ((tid & 63) == 0) rs[tid >> 6] = s;
  __syncthreads();
  if (tid == 0) si[row] = 1.f / ((rs[0] + rs[1]) + (rs[2] + rs[3]));
}

// ---------------------------------------------------------------------------
// Row-sum reciprocal, rows of 4096 fp16 (ET): si[row] = 1/sum
// ---------------------------------------------------------------------------
__global__ __launch_bounds__(256) void rsum_inv_4k(
    const unsigned short* __restrict__ ET, float* __restrict__ si)
{
  const int row = blockIdx.x;
  const int tid = threadIdx.x;
  const uint4* p = (const uint4*)(ET + (size_t)row * 4096);
  float s = 0.f;
#pragma unroll
  for (int h = 0; h < 2; ++h) {
    const uint4 u = p[tid * 2 + h];
    s += (h2f(u.x & 0xffff) + h2f(u.x >> 16)) + (h2f(u.y & 0xffff) + h2f(u.y >> 16)) +
         (h2f(u.z & 0xffff) + h2f(u.z >> 16)) + (h2f(u.w & 0xffff) + h2f(u.w >> 16));
  }
#pragma unroll
  for (int o = 32; o >= 1; o >>= 1) s += __shfl_xor(s, o);
  __shared__ float rs[4];
  if ((tid & 63) == 0) rs[tid >> 6] = s;
  __syncthreads();
  if (tid == 0) si[row] = 1.f / ((rs[0] + rs[1]) + (rs[2] + rs[3]));
}

// ---------------------------------------------------------------------------
// split-K x4 reduce of fp16 partials with diag scaling:
// O[b][dk][dv] = f16( (sum_s P[b*4+s][dk][dv]) * sk[b][dk] * sv[b][dv] )
// ---------------------------------------------------------------------------
__global__ __launch_bounds__(256) void red4m(
    const unsigned short* __restrict__ P, const float* __restrict__ sk,
    const float* __restrict__ sv, unsigned short* __restrict__ O)
{
  const int i = blockIdx.x * 256 + threadIdx.x;   // 2^20 groups of 4
  const int b = i >> 18;
  const int j = i & 262143;
  const int dk = j >> 8;
  const int dv0 = (j & 255) << 2;
  float s0 = 0, s1 = 0, s2 = 0, s3 = 0;
#pragma unroll
  for (int sl = 0; sl < 4; ++sl) {
    const uint2 u = *(const uint2*)(P + (((long)(b * 4 + sl)) << 20) + ((long)j << 2));
    s0 += h2f(u.x & 0xffff); s1 += h2f(u.x >> 16);
    s2 += h2f(u.y & 0xffff); s3 += h2f(u.y >> 16);
  }
  const float fk = sk[(b << 10) + dk];
  const float4 fv = *(const float4*)&sv[(b << 10) + dv0];
  unsigned short o4[4] = {f2h(s0 * fk * fv.x), f2h(s1 * fk * fv.y),
                          f2h(s2 * fk * fv.z), f2h(s3 * fk * fv.w)};
  *(uint2*)(O + ((long)b << 20) + ((long)j << 2)) = *(const uint2*)o4;
}

// ---------------------------------------------------------------------------
// split-K x4 reduce, plain: O[b][i] = f16(sum_s P[b*4+s][i])
// ---------------------------------------------------------------------------
__global__ __launch_bounds__(256) void red4h(
    const unsigned short* __restrict__ P, unsigned short* __restrict__ O)
{
  const int i = blockIdx.x * 256 + threadIdx.x;
  const int b = i >> 18;
  const int j = i & 262143;
  float s0 = 0, s1 = 0, s2 = 0, s3 = 0;
#pragma unroll
  for (int sl = 0; sl < 4; ++sl) {
    const uint2 u = *(const uint2*)(P + (((long)(b * 4 + sl)) << 20) + ((long)j << 2));
    s0 += h2f(u.x & 0xffff); s1 += h2f(u.x >> 16);
    s2 += h2f(u.y & 0xffff); s3 += h2f(u.y >> 16);
  }
  unsigned short o4[4] = {f2h(s0), f2h(s1), f2h(s2), f2h(s3)};
  *(uint2*)(O + ((long)b << 20) + ((long)j << 2)) = *(const uint2*)o4;
}

// ---------------------------------------------------------------------------
extern "C" void kernel_launch(void* const* d_in, const int* in_sizes, int n_in,
                              void* d_out, int out_size, void* d_ws, size_t ws_size,
                              hipStream_t stream) {
  const float* q  = (const float*)d_in[0];
  const float* k  = (const float*)d_in[1];
  const float* v  = (const float*)d_in[2];
  const float* Wq = (const float*)d_in[3];
  const float* bq = (const float*)d_in[4];
  const float* Wk = (const float*)d_in[5];
  const float* bk = (const float*)d_in[6];
  const float* Wv = (const float*)d_in[7];
  const float* bv = (const float*)d_in[8];
  const float* Wo = (const float*)d_in[9];
  const float* bo = (const float*)d_in[10];
  float* out = (float*)d_out;

  // workspace layout (~150 MB)
  char* p = (char*)d_ws;
  unsigned short* Part = (unsigned short*)p; p += 33554432;   // fp16 [16][1024][1024]
  unsigned short* WqT = (unsigned short*)p;  p += 2097152;
  unsigned short* WkT = (unsigned short*)p;  p += 2097152;
  unsigned short* WvT = (unsigned short*)p;  p += 2097152;
  unsigned short* WoT = (unsigned short*)p;  p += 2097152;
  unsigned short* Eq  = (unsigned short*)p;  p += 33554432;   // fp16 [4][4096][1024]
  unsigned short* ETk = (unsigned short*)p;  p += 33554432;   // fp16 [4][1024][4096]
  unsigned short* ETv = (unsigned short*)p;  p += 33554432;
  unsigned short* Mh  = (unsigned short*)p;  p += 8388608;    // fp16 [4][1024][1024]
  unsigned short* GTh = (unsigned short*)p;  p += 8388608;    // fp16 [4][1024][1024]
  float* sinvq = (float*)p; p += 16384 * 4;
  float* sk    = (float*)p; p += 4096 * 4;
  float* sv    = (float*)p; p += 4096 * 4;

  const dim3 blk(256);
  const dim3 blk512(512);
  const long S22 = 4096L * 1024;   // 2^22
  const long S20 = 1024L * 1024;   // 2^20

  // weights -> fp16 transposed
  w_trh<<<dim3(16, 16), blk, 0, stream>>>(Wq, WqT);
  w_trh<<<dim3(16, 16), blk, 0, stream>>>(Wk, WkT);
  w_trh<<<dim3(16, 16), blk, 0, stream>>>(Wv, WvT);
  w_trh<<<dim3(16, 16), blk, 0, stream>>>(Wo, WoT);

  // ---- Q path: Eq = exp(q@Wq + bq) (fp32 A, fused cvt); sinvq = 1/rowsum
  gemmt<1, 3><<<512, blk512, 0, stream>>>(q, WqT, Eq, bq, nullptr,
      1024, 1024, 1024, 4, 32, 1, S22, 0, S22);
  rsum_inv_1k<<<16384, blk, 0, stream>>>(Eq, sinvq);

  // ---- K path: ETk[b][d][l] = exp(k@Wk + bk)^T ; sk = 1/colsum
  gemmt<1, 4><<<512, blk512, 0, stream>>>(k, WkT, ETk, bk, nullptr,
      1024, 1024, 1024, 4, 32, 1, S22, 0, S22);
  rsum_inv_4k<<<4096, blk, 0, stream>>>(ETk, sk);

  // ---- V path
  gemmt<1, 4><<<512, blk512, 0, stream>>>(v, WvT, ETv, bv, nullptr,
      1024, 1024, 1024, 4, 32, 1, S22, 0, S22);
  rsum_inv_4k<<<4096, blk, 0, stream>>>(ETv, sv);

  // ---- Mraw partials: P[b*4+s] = ETk_chunk @ ETv_chunk^T (K=4096 split x4)
  //      Mh = f16(red4(P) * sk[dk] * sv[dv])
  gemmt<0, 2><<<512, blk512, 0, stream>>>(ETk, ETv, Part, nullptr, nullptr,
      1024, 1024, 4096, 4, 8, 4, S22, S22, S20);
  red4m<<<4096, blk, 0, stream>>>(Part, sk, sv, Mh);

  // ---- GT_b = (M_b @ Wo)^T = WoT @ M_b^T : K=1024 split x4
  gemmt<0, 2><<<512, blk512, 0, stream>>>(WoT, Mh, Part, nullptr, nullptr,
      1024, 256, 1024, 4, 8, 4, 0, S20, S20);
  red4h<<<4096, blk, 0, stream>>>(Part, GTh);

  // ---- Out_b = diag(sinvq) * (Eq_b @ GT_b^T) + bo
  gemmt<0, 5><<<512, blk512, 0, stream>>>(Eq, GTh, out, bo, sinvq,
      1024, 1024, 1024, 4, 32, 1, S22, S20, S22);

  (void)in_sizes; (void)n_in; (void)out_size; (void)ws_size;
}

// Round 13
// 301.524 us; speedup vs baseline: 1.0505x; 1.0505x over previous
//
#include <hip/hip_runtime.h>

typedef _Float16 f16x8 __attribute__((ext_vector_type(8)));
typedef float f32x4 __attribute__((ext_vector_type(4)));

__device__ __forceinline__ float h2f(unsigned short h) {
  return (float)__builtin_bit_cast(_Float16, h);
}
__device__ __forceinline__ unsigned short f2h(float f) {
  return __builtin_bit_cast(unsigned short, (_Float16)f);
}

__device__ __forceinline__ void gload_lds16(const void* g, void* l) {
  __builtin_amdgcn_global_load_lds(
      (const __attribute__((address_space(1))) void*)g,
      (__attribute__((address_space(3))) void*)l, 16, 0, 0);
}

// ---------------------------------------------------------------------------
// 128x256 tile GEMM, C = A @ Bt^T (fp16 MFMA, fp32 acc) — r11 proven core:
// single 48KB LDS buffer, 8 waves (2M x 4N), plain syncthreads loop,
// XOR-swizzled LDS (conflict-free ds_read_b128), XCD-swizzled 1D grid.
// ASRC 0: A fp16 via global_load_lds.  ASRC 1: A fp32, T14 reg-prefetch+cvt.
// OUTMODE 0: fp32 + bias[col]
//         2: fp16 split-K partial (slice zt), no bias
//         3: fp16 exp(acc+bias), [row][col] + FUSED row-sum -> atomicAdd sums
//         4: fp16 exp(acc+bias), TRANSPOSED ET[col][row] + FUSED col-sum ->
//            atomicAdd sums (shuffle-reduced partials, ~512 atomics/block)
//         5: fp32 acc/sums[row] + bias[col] (fused row-softmax + out; sums raw)
// ---------------------------------------------------------------------------
template <int ASRC, int OUTMODE>
__global__ __launch_bounds__(512, 4) void gemmt(
    const void* __restrict__ Av, const unsigned short* __restrict__ Bt,
    void* __restrict__ Cv, const float* __restrict__ bias,
    float* __restrict__ sums,
    int N, int K, int ldk, int gx, int gy, int nsplit,
    long sA, long sB, long sC)
{
  __shared__ alignas(16) unsigned char smem[49152];  // A 16KB | B 32KB
  const int tid  = threadIdx.x;
  const int lane = tid & 63;
  const int wave = tid >> 6;
  const int waveM = wave >> 2;      // 0..1 (64 rows each)
  const int waveN = wave & 3;       // 0..3 (64 cols each)

  // bijective XCD swizzle (nwg % 8 == 0 for all launches here)
  const int nwg = (int)gridDim.x;
  const int cpx = nwg >> 3;
  const int wg  = (int)blockIdx.x;
  const int w   = (wg & 7) * cpx + (wg >> 3);
  const int x   = w % gx;
  const int rem = w / gx;
  const int y   = rem % gy;
  const int zt  = rem / gy;
  const int bz  = zt / nsplit;
  const int sp  = zt % nsplit;

  const int m0 = y * 128, n0 = x * 256;
  const size_t ldkB = (size_t)ldk * 2;
  const size_t ldkB64 = ldkB * 64, ldkB128 = ldkB * 128;

  // staging addresses (dst linear tid*16 (+8192); src inverse-swizzled)
  const int srow = tid >> 3;                         // 0..63
  const int scol = ((tid * 16) & 127) ^ ((srow & 7) << 4);   // fp16-bytes
  const char* ApR16 = nullptr;   // ASRC==0
  const char* ApR32 = nullptr;   // ASRC==1
  const char* BpR;
  {
    const char* Bb = (const char*)(Bt + (long)bz * sB + (long)sp * K) + (size_t)n0 * ldkB;
    BpR = Bb + (size_t)srow * ldkB + scol;
    if (ASRC == 0) {
      const char* Ab = (const char*)Av + ((long)bz * sA + (long)sp * K) * 2
                       + (size_t)m0 * ldkB;
      ApR16 = Ab + (size_t)srow * ldkB + scol;
    } else {
      const char* Ab = (const char*)Av + ((long)bz * sA + (long)sp * K) * 4
                       + (size_t)m0 * (size_t)ldk * 4;
      ApR32 = Ab + (size_t)srow * (size_t)ldk * 4 + (size_t)scol * 2;
    }
  }
  const unsigned oA0 = (unsigned)tid * 16;
  const size_t ldk32_64 = (size_t)ldk * 4 * 64;      // 64 rows of fp32

  // ds_read byte offsets (kk=0); kk=1 offset = kk0 ^ 64 (bits 4-6 swizzle field)
  int offA[4], offB[4];
  {
    const int q16 = (lane >> 4) << 4;
#pragma unroll
    for (int mi = 0; mi < 4; ++mi) {
      const int r = waveM * 64 + mi * 16 + (lane & 15);
      offA[mi] = r * 128 + (q16 ^ ((r & 7) << 4));
    }
#pragma unroll
    for (int ni = 0; ni < 4; ++ni) {
      const int r = waveN * 64 + ni * 16 + (lane & 15);
      offB[ni] = 16384 + r * 128 + (q16 ^ ((r & 7) << 4));
    }
  }

  f32x4 acc[4][4] = {};

  // T14 prefetch registers (ASRC==1)
  float4 pf0, pf1, pf2, pf3;
  if (ASRC == 1) {
    const char* s0 = ApR32;
    const char* s1 = s0 + ldk32_64;
    pf0 = *(const float4*)s0;  pf1 = *(const float4*)(s0 + 16);
    pf2 = *(const float4*)s1;  pf3 = *(const float4*)(s1 + 16);
  }

  const int nk = K >> 6;
  for (int kt = 0; kt < nk; ++kt) {
    const size_t kb = (size_t)kt * 128;              // fp16 bytes per K-tile
    if (ASRC == 0) {
      gload_lds16(ApR16 + kb,           smem + oA0);
      gload_lds16(ApR16 + ldkB64 + kb,  smem + oA0 + 8192);
    } else {
      unsigned short h0[8], h1[8];
      const float* fa0 = (const float*)&pf0; const float* fa1 = (const float*)&pf1;
      const float* fb0 = (const float*)&pf2; const float* fb1 = (const float*)&pf3;
#pragma unroll
      for (int e = 0; e < 4; ++e) {
        h0[e] = f2h(fa0[e]); h0[4 + e] = f2h(fa1[e]);
        h1[e] = f2h(fb0[e]); h1[4 + e] = f2h(fb1[e]);
      }
      *(uint4*)&smem[oA0]        = *(const uint4*)h0;
      *(uint4*)&smem[oA0 + 8192] = *(const uint4*)h1;
      if (kt + 1 < nk) {
        const char* s0 = ApR32 + (size_t)(kt + 1) * 256;
        const char* s1 = s0 + ldk32_64;
        pf0 = *(const float4*)s0;  pf1 = *(const float4*)(s0 + 16);
        pf2 = *(const float4*)s1;  pf3 = *(const float4*)(s1 + 16);
      }
    }
    gload_lds16(BpR + kb,                     smem + 16384 + oA0);
    gload_lds16(BpR + ldkB64 + kb,            smem + 16384 + oA0 + 8192);
    gload_lds16(BpR + ldkB128 + kb,           smem + 16384 + oA0 + 16384);
    gload_lds16(BpR + ldkB128 + ldkB64 + kb,  smem + 16384 + oA0 + 24576);
    __syncthreads();
#pragma unroll
    for (int kk = 0; kk < 2; ++kk) {
      const int kx = kk << 6;
      f16x8 aF[4], bF[4];
#pragma unroll
      for (int mi = 0; mi < 4; ++mi) aF[mi] = *(const f16x8*)&smem[offA[mi] ^ kx];
#pragma unroll
      for (int ni = 0; ni < 4; ++ni) bF[ni] = *(const f16x8*)&smem[offB[ni] ^ kx];
#pragma unroll
      for (int mi = 0; mi < 4; ++mi)
#pragma unroll
        for (int ni = 0; ni < 4; ++ni)
          acc[mi][ni] = __builtin_amdgcn_mfma_f32_16x16x32_f16(aF[mi], bF[ni], acc[mi][ni], 0, 0, 0);
    }
    __syncthreads();
  }

  // ---- epilogue ----
  const int rb = (lane >> 4) * 4;
  const int cb_ = lane & 15;
  const long zout = (OUTMODE == 2) ? (long)zt : (long)bz;

  if (OUTMODE == 3) {
    // E store + fused row-sums (reduce over cb_ lanes, 4 waveN waves atomic)
#pragma unroll
    for (int m = 0; m < 4; ++m) {
      const int row0 = m0 + waveM * 64 + m * 16 + rb;
      float rs0 = 0, rs1 = 0, rs2 = 0, rs3 = 0;
#pragma unroll
      for (int n = 0; n < 4; ++n) {
        const int col = n0 + waveN * 64 + n * 16 + cb_;
        const float badd = bias[col];
        const float e0 = __expf(acc[m][n][0] + badd);
        const float e1 = __expf(acc[m][n][1] + badd);
        const float e2 = __expf(acc[m][n][2] + badd);
        const float e3 = __expf(acc[m][n][3] + badd);
        unsigned short* C16 = (unsigned short*)Cv;
        C16[zout * sC + (size_t)(row0 + 0) * N + col] = f2h(e0);
        C16[zout * sC + (size_t)(row0 + 1) * N + col] = f2h(e1);
        C16[zout * sC + (size_t)(row0 + 2) * N + col] = f2h(e2);
        C16[zout * sC + (size_t)(row0 + 3) * N + col] = f2h(e3);
        rs0 += e0; rs1 += e1; rs2 += e2; rs3 += e3;
      }
#pragma unroll
      for (int off = 1; off <= 8; off <<= 1) {
        rs0 += __shfl_xor(rs0, off);
        rs1 += __shfl_xor(rs1, off);
        rs2 += __shfl_xor(rs2, off);
        rs3 += __shfl_xor(rs3, off);
      }
      if ((lane & 15) == 0) {
        float* s = sums + (size_t)zout * 4096 + row0;
        atomicAdd(s + 0, rs0);
        atomicAdd(s + 1, rs1);
        atomicAdd(s + 2, rs2);
        atomicAdd(s + 3, rs3);
      }
    }
  } else if (OUTMODE == 4) {
    // transposed E store + fused col-sums (reduce over lane>>4, atomic)
    float cs[4] = {0.f, 0.f, 0.f, 0.f};
#pragma unroll
    for (int m = 0; m < 4; ++m) {
      const int row0 = m0 + waveM * 64 + m * 16 + rb;
#pragma unroll
      for (int n = 0; n < 4; ++n) {
        const int col = n0 + waveN * 64 + n * 16 + cb_;
        const float badd = bias[col];
        unsigned short o4[4];
        float ls = 0.f;
#pragma unroll
        for (int r = 0; r < 4; ++r) {
          const float e = __expf(acc[m][n][r] + badd);
          o4[r] = f2h(e);
          ls += e;
        }
        cs[n] += ls;
        *(uint2*)((unsigned short*)Cv + zout * sC + ((size_t)col << 12) + row0) =
            *(const uint2*)o4;
      }
    }
#pragma unroll
    for (int n = 0; n < 4; ++n) {
      cs[n] += __shfl_xor(cs[n], 16);
      cs[n] += __shfl_xor(cs[n], 32);
    }
    if (lane < 16) {
#pragma unroll
      for (int n = 0; n < 4; ++n) {
        const int col = n0 + waveN * 64 + n * 16 + lane;
        atomicAdd(sums + ((size_t)zout << 10) + col, cs[n]);
      }
    }
  } else {
#pragma unroll
    for (int m = 0; m < 4; ++m) {
      const int row0 = m0 + waveM * 64 + m * 16 + rb;
      float i0 = 0, i1 = 0, i2 = 0, i3 = 0;
      if (OUTMODE == 5) {
        const float4 s4 = *(const float4*)&sums[(size_t)zout * 4096 + row0];
        i0 = 1.0f / s4.x; i1 = 1.0f / s4.y; i2 = 1.0f / s4.z; i3 = 1.0f / s4.w;
      }
#pragma unroll
      for (int n = 0; n < 4; ++n) {
        const int col = n0 + waveN * 64 + n * 16 + cb_;
        if (OUTMODE == 2) {
#pragma unroll
          for (int r = 0; r < 4; ++r)
            ((unsigned short*)Cv)[zout * sC + (size_t)(row0 + r) * N + col] = f2h(acc[m][n][r]);
        } else if (OUTMODE == 5) {
          const float badd = bias[col];
          float* C32 = (float*)Cv;
          C32[zout * sC + (size_t)(row0 + 0) * N + col] = acc[m][n][0] * i0 + badd;
          C32[zout * sC + (size_t)(row0 + 1) * N + col] = acc[m][n][1] * i1 + badd;
          C32[zout * sC + (size_t)(row0 + 2) * N + col] = acc[m][n][2] * i2 + badd;
          C32[zout * sC + (size_t)(row0 + 3) * N + col] = acc[m][n][3] * i3 + badd;
        } else {
          const float badd = bias[col];
#pragma unroll
          for (int r = 0; r < 4; ++r)
            ((float*)Cv)[zout * sC + (size_t)(row0 + r) * N + col] = acc[m][n][r] + badd;
        }
      }
    }
  }
}

// ---------------------------------------------------------------------------
// Weight transpose + fp16: WT[c][r] = f16(W[r][c]), 1024x1024
// ---------------------------------------------------------------------------
__global__ __launch_bounds__(256) void w_trh(
    const float* __restrict__ W, unsigned short* __restrict__ WT)
{
  __shared__ unsigned short tile[64][73];
  const int c0 = blockIdx.x * 64;
  const int r0 = blockIdx.y * 64;
  const int tid = threadIdx.x;
  const int r = tid >> 2;
  const int cq = (tid & 3) * 16;
#pragma unroll
  for (int i = 0; i < 4; ++i) {
    const int c = cq + i * 4;
    const float4 v = *(const float4*)&W[(size_t)(r0 + r) * 1024 + c0 + c];
    tile[r][c + 0] = f2h(v.x);
    tile[r][c + 1] = f2h(v.y);
    tile[r][c + 2] = f2h(v.z);
    tile[r][c + 3] = f2h(v.w);
  }
  __syncthreads();
  const int c = tid >> 2;
  const int rq = (tid & 3) * 16;
  unsigned short outv[16];
#pragma unroll
  for (int j = 0; j < 16; ++j) outv[j] = tile[rq + j][c];
  unsigned short* Tb = WT + (size_t)(c0 + c) * 1024 + r0 + rq;
  ((uint4*)Tb)[0] = ((const uint4*)outv)[0];
  ((uint4*)Tb)[1] = ((const uint4*)outv)[1];
}

// ---------------------------------------------------------------------------
// split-K x4 reduce of fp16 partials with diag scaling from RAW sums:
// O[b][dk][dv] = f16( (sum_s P[..]) / skr[b][dk] / svr[b][dv] )
// ---------------------------------------------------------------------------
__global__ __launch_bounds__(256) void red4m(
    const unsigned short* __restrict__ P, const float* __restrict__ skr,
    const float* __restrict__ svr, unsigned short* __restrict__ O)
{
  const int i = blockIdx.x * 256 + threadIdx.x;   // 2^20 groups of 4
  const int b = i >> 18;
  const int j = i & 262143;
  const int dk = j >> 8;
  const int dv0 = (j & 255) << 2;
  float s0 = 0, s1 = 0, s2 = 0, s3 = 0;
#pragma unroll
  for (int sl = 0; sl < 4; ++sl) {
    const uint2 u = *(const uint2*)(P + (((long)(b * 4 + sl)) << 20) + ((long)j << 2));
    s0 += h2f(u.x & 0xffff); s1 += h2f(u.x >> 16);
    s2 += h2f(u.y & 0xffff); s3 += h2f(u.y >> 16);
  }
  const float fk = 1.0f / skr[(b << 10) + dk];
  const float4 fvr = *(const float4*)&svr[(b << 10) + dv0];
  unsigned short o4[4] = {f2h(s0 * fk / fvr.x), f2h(s1 * fk / fvr.y),
                          f2h(s2 * fk / fvr.z), f2h(s3 * fk / fvr.w)};
  *(uint2*)(O + ((long)b << 20) + ((long)j << 2)) = *(const uint2*)o4;
}

// ---------------------------------------------------------------------------
// split-K x4 reduce, plain: O[b][i] = f16(sum_s P[b*4+s][i])
// ---------------------------------------------------------------------------
__global__ __launch_bounds__(256) void red4h(
    const unsigned short* __restrict__ P, unsigned short* __restrict__ O)
{
  const int i = blockIdx.x * 256 + threadIdx.x;
  const int b = i >> 18;
  const int j = i & 262143;
  float s0 = 0, s1 = 0, s2 = 0, s3 = 0;
#pragma unroll
  for (int sl = 0; sl < 4; ++sl) {
    const uint2 u = *(const uint2*)(P + (((long)(b * 4 + sl)) << 20) + ((long)j << 2));
    s0 += h2f(u.x & 0xffff); s1 += h2f(u.x >> 16);
    s2 += h2f(u.y & 0xffff); s3 += h2f(u.y >> 16);
  }
  unsigned short o4[4] = {f2h(s0), f2h(s1), f2h(s2), f2h(s3)};
  *(uint2*)(O + ((long)b << 20) + ((long)j << 2)) = *(const uint2*)o4;
}

// ---------------------------------------------------------------------------
extern "C" void kernel_launch(void* const* d_in, const int* in_sizes, int n_in,
                              void* d_out, int out_size, void* d_ws, size_t ws_size,
                              hipStream_t stream) {
  const float* q  = (const float*)d_in[0];
  const float* k  = (const float*)d_in[1];
  const float* v  = (const float*)d_in[2];
  const float* Wq = (const float*)d_in[3];
  const float* bq = (const float*)d_in[4];
  const float* Wk = (const float*)d_in[5];
  const float* bk = (const float*)d_in[6];
  const float* Wv = (const float*)d_in[7];
  const float* bv = (const float*)d_in[8];
  const float* Wo = (const float*)d_in[9];
  const float* bo = (const float*)d_in[10];
  float* out = (float*)d_out;

  // workspace layout (~150 MB)
  char* p = (char*)d_ws;
  unsigned short* Part = (unsigned short*)p; p += 33554432;   // fp16 [16][1024][1024]
  unsigned short* WqT = (unsigned short*)p;  p += 2097152;
  unsigned short* WkT = (unsigned short*)p;  p += 2097152;
  unsigned short* WvT = (unsigned short*)p;  p += 2097152;
  unsigned short* WoT = (unsigned short*)p;  p += 2097152;
  unsigned short* Eq  = (unsigned short*)p;  p += 33554432;   // fp16 [4][4096][1024]
  unsigned short* ETk = (unsigned short*)p;  p += 33554432;   // fp16 [4][1024][4096]
  unsigned short* ETv = (unsigned short*)p;  p += 33554432;
  unsigned short* Mh  = (unsigned short*)p;  p += 8388608;    // fp16 [4][1024][1024]
  unsigned short* GTh = (unsigned short*)p;  p += 8388608;    // fp16 [4][1024][1024]
  float* sqraw = (float*)p; p += 16384 * 4;   // raw row-sums of Eq
  float* skraw = (float*)p; p += 4096 * 4;    // raw col-sums of Ek
  float* svraw = (float*)p; p += 4096 * 4;    // raw col-sums of Ev

  const dim3 blk(256);
  const dim3 blk512(512);
  const long S22 = 4096L * 1024;   // 2^22
  const long S20 = 1024L * 1024;   // 2^20

  // zero the atomic sum accumulators (96 KB; graph-capturable)
  hipMemsetAsync(sqraw, 0, (16384 + 4096 + 4096) * sizeof(float), stream);

  // weights -> fp16 transposed
  w_trh<<<dim3(16, 16), blk, 0, stream>>>(Wq, WqT);
  w_trh<<<dim3(16, 16), blk, 0, stream>>>(Wk, WkT);
  w_trh<<<dim3(16, 16), blk, 0, stream>>>(Wv, WvT);
  w_trh<<<dim3(16, 16), blk, 0, stream>>>(Wo, WoT);

  // ---- Q path: Eq = exp(q@Wq + bq) + fused row-sums -> sqraw
  gemmt<1, 3><<<512, blk512, 0, stream>>>(q, WqT, Eq, bq, sqraw,
      1024, 1024, 1024, 4, 32, 1, S22, 0, S22);

  // ---- K path: ETk[b][d][l] = exp(k@Wk + bk)^T + fused col-sums -> skraw
  gemmt<1, 4><<<512, blk512, 0, stream>>>(k, WkT, ETk, bk, skraw,
      1024, 1024, 1024, 4, 32, 1, S22, 0, S22);

  // ---- V path
  gemmt<1, 4><<<512, blk512, 0, stream>>>(v, WvT, ETv, bv, svraw,
      1024, 1024, 1024, 4, 32, 1, S22, 0, S22);

  // ---- Mraw partials: P[b*4+s] = ETk_chunk @ ETv_chunk^T (K=4096 split x4)
  //      Mh = f16(red4(P) / skraw[dk] / svraw[dv])
  gemmt<0, 2><<<512, blk512, 0, stream>>>(ETk, ETv, Part, nullptr, nullptr,
      1024, 1024, 4096, 4, 8, 4, S22, S22, S20);
  red4m<<<4096, blk, 0, stream>>>(Part, skraw, svraw, Mh);

  // ---- GT_b = (M_b @ Wo)^T = WoT @ M_b^T : K=1024 split x4
  gemmt<0, 2><<<512, blk512, 0, stream>>>(WoT, Mh, Part, nullptr, nullptr,
      1024, 256, 1024, 4, 8, 4, 0, S20, S20);
  red4h<<<4096, blk, 0, stream>>>(Part, GTh);

  // ---- Out_b = diag(1/sqraw) * (Eq_b @ GT_b^T) + bo
  gemmt<0, 5><<<512, blk512, 0, stream>>>(Eq, GTh, out, bo, sqraw,
      1024, 1024, 1024, 4, 32, 1, S22, S20, S22);

  (void)in_sizes; (void)n_in; (void)out_size; (void)ws_size;
}